// Round 12
// baseline (134.385 us; speedup 1.0000x reference)
//
#include <hip/hip_runtime.h>
#include <stdint.h>

#define IN_F 2048
#define OUT_F 2048
#define BM 128
#define BN 128
#define NT 16               // K-tiles of 128 bytes

typedef int v4i  __attribute__((ext_vector_type(4)));
typedef int v16i __attribute__((ext_vector_type(16)));

__device__ __forceinline__ void gload_lds16(const void* g, void* l) {
    __builtin_amdgcn_global_load_lds(
        (const __attribute__((address_space(1))) void*)g,
        (__attribute__((address_space(3))) void*)l, 16, 0, 0);
}

// ---------------- Kernel 1: smooth-scale + per-token int8 quant ----------------
__global__ __launch_bounds__(256) void quant_kernel(
    const float* __restrict__ x, const float* __restrict__ ss,
    int8_t* __restrict__ xq, float* __restrict__ xscale, int T)
{
    const int wave = threadIdx.x >> 6;
    const int lane = threadIdx.x & 63;
    const int t = blockIdx.x * 4 + wave;
    if (t >= T) return;

    const float4* xrow = (const float4*)(x + (size_t)t * IN_F);
    const float4* ssv  = (const float4*)ss;

    float4 vals[8];
    float amax = 0.f;
#pragma unroll
    for (int it = 0; it < 8; ++it) {
        int idx = it * 64 + lane;
        float4 v = xrow[idx];
        float4 s = ssv[idx];
        v.x *= s.x; v.y *= s.y; v.z *= s.z; v.w *= s.w;
        vals[it] = v;
        amax = fmaxf(amax, fmaxf(fmaxf(fabsf(v.x), fabsf(v.y)),
                                 fmaxf(fabsf(v.z), fabsf(v.w))));
    }
#pragma unroll
    for (int o = 32; o; o >>= 1) amax = fmaxf(amax, __shfl_xor(amax, o, 64));

    float scale = fmaxf(amax * (1.0f / 127.0f), 1e-8f);
    float inv = 1.0f / scale;
    if (lane == 0) xscale[t] = scale;

    int* out = (int*)(xq + (size_t)t * IN_F);
#pragma unroll
    for (int it = 0; it < 8; ++it) {
        float4 v = vals[it];
        int q0 = (int)fminf(fmaxf(rintf(v.x * inv), -128.f), 127.f);
        int q1 = (int)fminf(fmaxf(rintf(v.y * inv), -128.f), 127.f);
        int q2 = (int)fminf(fmaxf(rintf(v.z * inv), -128.f), 127.f);
        int q3 = (int)fminf(fmaxf(rintf(v.w * inv), -128.f), 127.f);
        out[it * 64 + lane] = (q0 & 255) | ((q1 & 255) << 8) |
                              ((q2 & 255) << 16) | ((q3 & 255) << 24);
    }
}

// ---------------- Kernel 2: pack W into MFMA-fragment order ----------------
// Fragment (colblk, kt, ks), lane l holds 16B: col = colblk*32 + (l&31),
// k = kt*128 + ks*32 + (l>>5)*16 + 0..15.  Byte addr = colblk*65536 + kt*4096
// + ks*1024 + l*16.
__global__ __launch_bounds__(256) void pack_wfrag_kernel(
    const int* __restrict__ w, int8_t* __restrict__ w8f)
{
    const int tau = blockIdx.x * 256 + threadIdx.x;
    const int lane = tau & 63;
    const int rest = tau >> 6;
    const int ks = rest & 3;
    const int kt = (rest >> 2) & 15;
    const int colblk = rest >> 6;
    const int col = colblk * 32 + (lane & 31);
    const int kbase = kt * 128 + ks * 32 + (lane >> 5) * 16;
    const int* src = w + (size_t)col * IN_F + kbase;
    int out[4];
#pragma unroll
    for (int d = 0; d < 4; ++d) {
        int4 v = *(const int4*)(src + d * 4);
        out[d] = (v.x & 255) | ((v.y & 255) << 8) |
                 ((v.z & 255) << 16) | ((v.w & 255) << 24);
    }
    *(int4*)(w8f + (size_t)tau * 16) = *(const int4*)out;
}

// ---------------- Kernel 3: 128x128, 4 waves, TLP-first i8 GEMM -----------------
// 4 blocks/CU x 4 waves = 4 waves/SIMD: latency hidden by occupancy, not
// scheduling. Wave tile 64x64 (acc[2][2] v16i = 64 regs). A in LDS
// fragment-linear (2 bufs x 16KB, zero-conflict 1KB wave accesses); B direct
// from L2 (fragment-packed), single reg set. Per tile: STA(t+1), vmcnt(4)
// [drains B(t)], ds/MFMA, LOADB(t+1), vmcnt(8) [drains STA, leaves B], bar.
__global__ __launch_bounds__(256, 4) void gemm_kernel(
    const int8_t* __restrict__ Ag,
    const int8_t* __restrict__ Bf,
    const float* __restrict__ xscale,
    const float* __restrict__ wscale,
    const float* __restrict__ bias,
    float* __restrict__ C, int M)
{
    __shared__ __align__(16) int8_t smem[2 * 16384];   // 32 KB

    const int tid  = threadIdx.x;
    const int lane = tid & 63;
    const int wave = tid >> 6;
    const int wr = wave >> 1;          // 0..1 (M half, 64 rows)
    const int wc = wave & 1;           // 0..1 (N half, 64 cols)
    const int l31 = lane & 31, hi2 = lane >> 5;

    // XCD-bijective swizzle: 2048 blocks, 8 XCDs, 256 per chunk
    const int lb  = blockIdx.x;
    const int swb = (lb & 7) * 256 + (lb >> 3);
    const int bm = swb >> 4;           // 0..127
    const int bn = swb & 15;           // 0..15
    const size_t arow0 = (size_t)bm * BM;

    // A staging: instr J stages frags J*4..J*4+3 (gg=J, ks=tid>>6).
    // thread tid -> global (arow0 + J*32 + l31)*2048 + T*128 + (tid>>6)*32 + hi2*16
    const size_t a_gbase = (arow0 + l31) * 2048 + (size_t)(tid >> 6) * 32
                           + (size_t)hi2 * 16;

#define STA(BUF, T)                                                              \
    do { _Pragma("unroll") for (int J_ = 0; J_ < 4; ++J_)                        \
        gload_lds16(Ag + a_gbase + (size_t)J_ * 32 * 2048 + (T) * 128,           \
                    (int8_t*)smem + (BUF) * 16384 + J_ * 4096 + tid * 16);       \
    } while (0)

    // B: wave (wc) owns colblks bn*4 + wc*2 + {0,1}
    const int8_t* bbase = Bf + (size_t)(bn * 4 + wc * 2) * 65536 + lane * 16;

#define LOADB(T)                                                                 \
    do { _Pragma("unroll") for (int n_ = 0; n_ < 2; ++n_)                        \
         _Pragma("unroll") for (int k_ = 0; k_ < 4; ++k_)                        \
        b[n_][k_] = *(const v4i*)(bbase + n_ * 65536 + (T) * 4096 + k_ * 1024);  \
    } while (0)

    // A-frag ds_read: frag = (wr*2+m)*4+ks at frag*1024 + lane*16 (1KB/wave)
#define RDA(DST, KS)                                                             \
    do { _Pragma("unroll") for (int m_ = 0; m_ < 2; ++m_)                        \
        DST[m_] = *(const v4i*)((const int8_t*)smem + cur * 16384 +              \
                                (((wr * 2 + m_) * 4 + (KS)) << 10) + lane * 16); \
    } while (0)

    // dep-distance-4 MFMA order per ks: m0n0, m0n1, m1n0, m1n1
#define MF(AF, KS)                                                               \
    do { _Pragma("unroll") for (int m_ = 0; m_ < 2; ++m_)                        \
         _Pragma("unroll") for (int n_ = 0; n_ < 2; ++n_)                        \
        acc[m_][n_] = __builtin_amdgcn_mfma_i32_32x32x32_i8(                     \
            AF[m_], b[n_][KS], acc[m_][n_], 0, 0, 0); } while (0)

#define BAR __builtin_amdgcn_s_barrier()
#define VMW(N) asm volatile("s_waitcnt vmcnt(" #N ")" ::: "memory")

// Ledger: enter tile t (t>0) with 8 B(t) outstanding, A(t) complete.
// STA(t+1)[4] -> 12; vmcnt(4) drains B(t) (oldest 8), leaves STA 4.
// compute; LOADB(t+1)[8] -> 12; vmcnt(8) drains STA(t+1), leaves B(t+1) 8; bar.
#define KT(T)                                                                    \
    do {                                                                         \
        const int cur = (T) & 1;                                                 \
        if ((T) < 15) STA(cur ^ 1, (T) + 1);                                     \
        if ((T) > 0) { if ((T) < 15) VMW(4); else VMW(0); }                      \
        v4i a0[2], a1[2];                                                        \
        RDA(a0, 0);                                                              \
        RDA(a1, 1); MF(a0, 0);                                                   \
        RDA(a0, 2); MF(a1, 1);                                                   \
        RDA(a1, 3); MF(a0, 2);                                                   \
        MF(a1, 3);                                                               \
        if ((T) < 15) {                                                          \
            LOADB((T) + 1);                                                      \
            VMW(8);                                                              \
            BAR;                                                                 \
        }                                                                        \
    } while (0)

    v16i acc[2][2] = {};
    v4i b[2][4];

    // prologue: A(0)->buf0, B(0)->regs; drain everything; barrier.
    STA(0, 0);
    LOADB(0);
    VMW(0);
    BAR;

    KT(0);  KT(1);  KT(2);  KT(3);
    KT(4);  KT(5);  KT(6);  KT(7);
    KT(8);  KT(9);  KT(10); KT(11);
    KT(12); KT(13); KT(14); KT(15);

    // epilogue: 32x32 C/D layout col = lane&31, row = (reg&3)+8*(reg>>2)+4*hi2
    float wsc[2], bs[2];
    int gcol[2];
#pragma unroll
    for (int n = 0; n < 2; ++n) {
        gcol[n] = bn * BN + wc * 64 + n * 32 + l31;
        wsc[n] = wscale[gcol[n]];
        bs[n]  = bias[gcol[n]];
    }
#pragma unroll
    for (int m = 0; m < 2; ++m) {
#pragma unroll
        for (int reg = 0; reg < 16; ++reg) {
            const int row = (reg & 3) + 8 * (reg >> 2) + 4 * hi2;
            const size_t grow = arow0 + wr * 64 + m * 32 + row;
            const float xs = xscale[grow];
            float* crow = C + grow * OUT_F;
#pragma unroll
            for (int n = 0; n < 2; ++n)
                __builtin_nontemporal_store(
                    (float)acc[m][n][reg] * xs * wsc[n] + bs[n], crow + gcol[n]);
        }
    }
#undef STA
#undef LOADB
#undef RDA
#undef MF
#undef KT
}

extern "C" void kernel_launch(void* const* d_in, const int* in_sizes, int n_in,
                              void* d_out, int out_size, void* d_ws, size_t ws_size,
                              hipStream_t stream)
{
    const float* x      = (const float*)d_in[0];
    const float* ss     = (const float*)d_in[1];
    const float* wscale = (const float*)d_in[2];
    const float* bias   = (const float*)d_in[3];
    const int*   w32    = (const int*)d_in[4];
    float* out = (float*)d_out;

    const int T = in_sizes[0] / IN_F;   // 16384

    int8_t* xq     = (int8_t*)d_ws;
    float*  xscale = (float*)((char*)d_ws + (size_t)T * IN_F);
    int8_t* w8f    = (int8_t*)((char*)d_ws + (size_t)T * IN_F + (size_t)T * 4);

    quant_kernel<<<dim3((T + 3) / 4), dim3(256), 0, stream>>>(x, ss, xq, xscale, T);
    pack_wfrag_kernel<<<dim3(1024), dim3(256), 0, stream>>>(w32, w8f);
    gemm_kernel<<<dim3((T / BM) * (OUT_F / BN)), dim3(256), 0, stream>>>(
        xq, w8f, xscale, wscale, bias, out, T);
}

// Round 14
// 115.469 us; speedup vs baseline: 1.1638x; 1.1638x over previous
//
#include <hip/hip_runtime.h>
#include <stdint.h>

#define IN_F 2048
#define OUT_F 2048
#define BM 128
#define BN 128
#define NT 16               // K-tiles of 128 bytes

typedef int v4i  __attribute__((ext_vector_type(4)));

__device__ __forceinline__ void gload_lds16(const void* g, void* l) {
    __builtin_amdgcn_global_load_lds(
        (const __attribute__((address_space(1))) void*)g,
        (__attribute__((address_space(3))) void*)l, 16, 0, 0);
}

// ---------------- Kernel 1: smooth-scale + per-token int8 quant ----------------
__global__ __launch_bounds__(256) void quant_kernel(
    const float* __restrict__ x, const float* __restrict__ ss,
    int8_t* __restrict__ xq, float* __restrict__ xscale, int T)
{
    const int wave = threadIdx.x >> 6;
    const int lane = threadIdx.x & 63;
    const int t = blockIdx.x * 4 + wave;
    if (t >= T) return;

    const float4* xrow = (const float4*)(x + (size_t)t * IN_F);
    const float4* ssv  = (const float4*)ss;

    float4 vals[8];
    float amax = 0.f;
#pragma unroll
    for (int it = 0; it < 8; ++it) {
        int idx = it * 64 + lane;
        float4 v = xrow[idx];
        float4 s = ssv[idx];
        v.x *= s.x; v.y *= s.y; v.z *= s.z; v.w *= s.w;
        vals[it] = v;
        amax = fmaxf(amax, fmaxf(fmaxf(fabsf(v.x), fabsf(v.y)),
                                 fmaxf(fabsf(v.z), fabsf(v.w))));
    }
#pragma unroll
    for (int o = 32; o; o >>= 1) amax = fmaxf(amax, __shfl_xor(amax, o, 64));

    float scale = fmaxf(amax * (1.0f / 127.0f), 1e-8f);
    float inv = 1.0f / scale;
    if (lane == 0) xscale[t] = scale;

    int* out = (int*)(xq + (size_t)t * IN_F);
#pragma unroll
    for (int it = 0; it < 8; ++it) {
        float4 v = vals[it];
        int q0 = (int)fminf(fmaxf(rintf(v.x * inv), -128.f), 127.f);
        int q1 = (int)fminf(fmaxf(rintf(v.y * inv), -128.f), 127.f);
        int q2 = (int)fminf(fmaxf(rintf(v.z * inv), -128.f), 127.f);
        int q3 = (int)fminf(fmaxf(rintf(v.w * inv), -128.f), 127.f);
        out[it * 64 + lane] = (q0 & 255) | ((q1 & 255) << 8) |
                              ((q2 & 255) << 16) | ((q3 & 255) << 24);
    }
}

// ---------------- Kernel 2: pack W into 16x16x64 MFMA-fragment order ------------
// Fragment (colblk16, kt, ks64): lane l holds 16B: col = colblk*16 + (l&15),
// k = kt*128 + ks*64 + (l>>4)*16 + 0..15.
// Byte addr = colblk*32768 + kt*2048 + ks*1024 + l*16.
__global__ __launch_bounds__(256) void pack_wfrag_kernel(
    const int* __restrict__ w, int8_t* __restrict__ w8f)
{
    const int tau = blockIdx.x * 256 + threadIdx.x;   // 0..262143
    const int lane = tau & 63;
    const int rest = tau >> 6;        // fragid = colblk*32 + kt*2 + ks
    const int ks = rest & 1;
    const int kt = (rest >> 1) & 15;
    const int colblk = rest >> 5;
    const int col = colblk * 16 + (lane & 15);
    const int kbase = kt * 128 + ks * 64 + (lane >> 4) * 16;
    const int* src = w + (size_t)col * IN_F + kbase;
    int out[4];
#pragma unroll
    for (int d = 0; d < 4; ++d) {
        int4 v = *(const int4*)(src + d * 4);
        out[d] = (v.x & 255) | ((v.y & 255) << 8) |
                 ((v.z & 255) << 16) | ((v.w & 255) << 24);
    }
    *(int4*)(w8f + (size_t)tau * 16) = *(const int4*)out;
}

// ---------------- Kernel 3: 128x128, 4 waves, 16x16x64 i8 GEMM ------------------
// R7 structure with the SHORT MFMA: wave tile 64x64 (mrep=4, nrep=4, acc[4][4]
// i32x4 = 64 regs). A in LDS 3-deep (16KB slots, R7's proven row+granule-swizzle
// staging); B direct from L2 (16-col fragment pack), ping-pong regs. Ledger
// identical to R7: per tile LOADB(t+1)[8], STA(t+2)[4], compute, vmcnt(4), bar.
__global__ __launch_bounds__(256, 2) void gemm_kernel(
    const int8_t* __restrict__ Ag,
    const int8_t* __restrict__ Bf,
    const float* __restrict__ xscale,
    const float* __restrict__ wscale,
    const float* __restrict__ bias,
    float* __restrict__ C, int M)
{
    __shared__ __align__(16) int8_t smem[3 * 16384];   // 48 KB: 3 A-slots

    const int tid  = threadIdx.x;
    const int lane = tid & 63;
    const int wave = tid >> 6;
    const int wr = wave >> 1;          // 0..1 (M half, 64 rows)
    const int wc = wave & 1;           // 0..1 (N half, 64 cols)
    const int l15 = lane & 15, hi = lane >> 4;   // hi 0..3
    const int asw = l15 & 7;

    // XCD-bijective swizzle: 2048 blocks, 8 XCDs, 256 per chunk
    const int lb  = blockIdx.x;
    const int swb = (lb & 7) * 256 + (lb >> 3);
    const int bm = swb >> 4;           // 0..127
    const int bn = swb & 15;           // 0..15
    const size_t arow0 = (size_t)bm * BM;

    // A staging (R7): thread covers rows (tid>>3)+32*i, LDS slot (tid&7),
    // global granule pre-swizzled by (row&7)
    const int st_r = tid >> 3;
    const int st_c = ((tid & 7) ^ ((tid >> 3) & 7)) << 4;

#define STA(SLOTI, T)                                                            \
    do { _Pragma("unroll") for (int i_ = 0; i_ < 4; ++i_)                        \
        gload_lds16(Ag + (arow0 + i_ * 32 + st_r) * (size_t)IN_F                 \
                        + (size_t)((T) * 128) + st_c,                            \
                    (int8_t*)smem + (SLOTI) * 16384 + i_ * 4096 + tid * 16);     \
    } while (0)

    // B: wave (wc) owns colblks bn*8 + wc*4 + {0..3} (stride 32768 B)
    const int8_t* bbase = Bf + (size_t)(bn * 8 + wc * 4) * 32768 + lane * 16;

#define LOADB(DST, T)                                                            \
    do { _Pragma("unroll") for (int n_ = 0; n_ < 4; ++n_)                        \
         _Pragma("unroll") for (int k_ = 0; k_ < 2; ++k_)                        \
        DST[n_][k_] = *(const v4i*)(bbase + n_ * 32768 + (T) * 2048 + k_ * 1024);\
    } while (0)

    // A-frag ds_read (16x16x64): row = wr*64 + m*16 + l15 (row&7 == l15&7),
    // granule g = ks*4 + hi, swizzled slot = g ^ (l15&7)
#define RDA(DST, KS)                                                             \
    do { _Pragma("unroll") for (int m_ = 0; m_ < 4; ++m_)                        \
        DST[m_] = *(const v4i*)((const int8_t*)smem + cur * 16384 +              \
                                (wr * 64 + m_ * 16 + l15) * 128 +                \
                                ((((KS) * 4 + hi) ^ asw) << 4)); } while (0)

#define MF16(AF, B, KS)                                                          \
    do { __builtin_amdgcn_s_setprio(1);                                          \
        _Pragma("unroll") for (int m_ = 0; m_ < 4; ++m_)                         \
        _Pragma("unroll") for (int n_ = 0; n_ < 4; ++n_)                         \
            acc[m_][n_] = __builtin_amdgcn_mfma_i32_16x16x64_i8(                 \
                AF[m_], B[n_][KS], acc[m_][n_], 0, 0, 0);                        \
        __builtin_amdgcn_s_setprio(0); } while (0)

#define BAR __builtin_amdgcn_s_barrier()
#define VMW(N) asm volatile("s_waitcnt vmcnt(" #N ")" ::: "memory")

// Ledger (= R7): per tile issue LOADB(t+1)[8] then STA(t+2)[4]; end-of-tile
// vmcnt(4) drains S(t+1)+B(t+1), leaves S(t+2) in flight. Tail: t=14 vmcnt(0).
#define KT(T, BCUR, BNXT)                                                        \
    do {                                                                         \
        const int cur = (T) % 3;                                                 \
        if ((T) <= 14) LOADB(BNXT, (T) + 1);                                     \
        if ((T) <= 13) STA(((T) + 2) % 3, (T) + 2);                              \
        v4i a0[4], a1[4];                                                        \
        RDA(a0, 0);                                                              \
        RDA(a1, 1); MF16(a0, BCUR, 0);                                           \
        MF16(a1, BCUR, 1);                                                       \
        if ((T) <= 13) { VMW(4); BAR; }                                          \
        else if ((T) == 14) { VMW(0); BAR; }                                     \
    } while (0)

    v4i acc[4][4] = {};
    v4i B0[4][2], B1[4][2];

    // prologue: S(0)->slot0 [4], B(0) [8], S(1)->slot1 [4]; vmcnt(4) leaves S(1).
    STA(0, 0);
    LOADB(B0, 0);
    STA(1, 1);
    VMW(4);
    BAR;

    KT(0,  B0, B1); KT(1,  B1, B0); KT(2,  B0, B1); KT(3,  B1, B0);
    KT(4,  B0, B1); KT(5,  B1, B0); KT(6,  B0, B1); KT(7,  B1, B0);
    KT(8,  B0, B1); KT(9,  B1, B0); KT(10, B0, B1); KT(11, B1, B0);
    KT(12, B0, B1); KT(13, B1, B0); KT(14, B0, B1); KT(15, B1, B0);

    // epilogue: 16x16 C/D layout col = lane&15, row = hi*4 + reg
    float wsc[4], bs[4];
    int gcol[4];
#pragma unroll
    for (int n = 0; n < 4; ++n) {
        gcol[n] = bn * BN + wc * 64 + n * 16 + l15;
        wsc[n] = wscale[gcol[n]];
        bs[n]  = bias[gcol[n]];
    }
#pragma unroll
    for (int m = 0; m < 4; ++m) {
#pragma unroll
        for (int r = 0; r < 4; ++r) {
            const size_t grow = arow0 + wr * 64 + m * 16 + hi * 4 + r;
            const float xs = xscale[grow];
            float* crow = C + grow * OUT_F;
#pragma unroll
            for (int n = 0; n < 4; ++n)
                __builtin_nontemporal_store(
                    (float)acc[m][n][r] * xs * wsc[n] + bs[n], crow + gcol[n]);
        }
    }
#undef STA
#undef LOADB
#undef RDA
#undef MF16
#undef KT
}

extern "C" void kernel_launch(void* const* d_in, const int* in_sizes, int n_in,
                              void* d_out, int out_size, void* d_ws, size_t ws_size,
                              hipStream_t stream)
{
    const float* x      = (const float*)d_in[0];
    const float* ss     = (const float*)d_in[1];
    const float* wscale = (const float*)d_in[2];
    const float* bias   = (const float*)d_in[3];
    const int*   w32    = (const int*)d_in[4];
    float* out = (float*)d_out;

    const int T = in_sizes[0] / IN_F;   // 16384

    int8_t* xq     = (int8_t*)d_ws;
    float*  xscale = (float*)((char*)d_ws + (size_t)T * IN_F);
    int8_t* w8f    = (int8_t*)((char*)d_ws + (size_t)T * IN_F + (size_t)T * 4);

    quant_kernel<<<dim3((T + 3) / 4), dim3(256), 0, stream>>>(x, ss, xq, xscale, T);
    pack_wfrag_kernel<<<dim3(1024), dim3(256), 0, stream>>>(w32, w8f);
    gemm_kernel<<<dim3((T / BM) * (OUT_F / BN)), dim3(256), 0, stream>>>(
        xq, w8f, xscale, wscale, bias, out, T);
}

// Round 15
// 112.991 us; speedup vs baseline: 1.1893x; 1.0219x over previous
//
#include <hip/hip_runtime.h>
#include <stdint.h>

#define IN_F 2048
#define OUT_F 2048
#define BM 256
#define BN 256

typedef int v4i __attribute__((ext_vector_type(4)));

__device__ __forceinline__ void gload_lds16(const void* g, void* l) {
    __builtin_amdgcn_global_load_lds(
        (const __attribute__((address_space(1))) void*)g,
        (__attribute__((address_space(3))) void*)l, 16, 0, 0);
}

// ---------------- Kernel 1: smooth-scale + per-token int8 quant ----------------
__global__ __launch_bounds__(256) void quant_kernel(
    const float* __restrict__ x, const float* __restrict__ ss,
    int8_t* __restrict__ xq, float* __restrict__ xscale, int T)
{
    const int wave = threadIdx.x >> 6;
    const int lane = threadIdx.x & 63;
    const int t = blockIdx.x * 4 + wave;
    if (t >= T) return;

    const float4* xrow = (const float4*)(x + (size_t)t * IN_F);
    const float4* ssv  = (const float4*)ss;

    float4 vals[8];
    float amax = 0.f;
#pragma unroll
    for (int it = 0; it < 8; ++it) {
        int idx = it * 64 + lane;
        float4 v = xrow[idx];
        float4 s = ssv[idx];
        v.x *= s.x; v.y *= s.y; v.z *= s.z; v.w *= s.w;
        vals[it] = v;
        amax = fmaxf(amax, fmaxf(fmaxf(fabsf(v.x), fabsf(v.y)),
                                 fmaxf(fabsf(v.z), fabsf(v.w))));
    }
#pragma unroll
    for (int o = 32; o; o >>= 1) amax = fmaxf(amax, __shfl_xor(amax, o, 64));

    float scale = fmaxf(amax * (1.0f / 127.0f), 1e-8f);
    float inv = 1.0f / scale;
    if (lane == 0) xscale[t] = scale;

    int* out = (int*)(xq + (size_t)t * IN_F);
#pragma unroll
    for (int it = 0; it < 8; ++it) {
        float4 v = vals[it];
        int q0 = (int)fminf(fmaxf(rintf(v.x * inv), -128.f), 127.f);
        int q1 = (int)fminf(fmaxf(rintf(v.y * inv), -128.f), 127.f);
        int q2 = (int)fminf(fmaxf(rintf(v.z * inv), -128.f), 127.f);
        int q3 = (int)fminf(fmaxf(rintf(v.w * inv), -128.f), 127.f);
        out[it * 64 + lane] = (q0 & 255) | ((q1 & 255) << 8) |
                              ((q2 & 255) << 16) | ((q3 & 255) << 24);
    }
}

// ---------------- Kernel 2: pack int32 weights -> int8 row-major ----------------
__global__ __launch_bounds__(256) void pack_w_kernel(
    const int* __restrict__ w, int8_t* __restrict__ w8, int n4)
{
    int i = blockIdx.x * blockDim.x + threadIdx.x;
    if (i < n4) {
        int4 v = ((const int4*)w)[i];
        ((int*)w8)[i] = (v.x & 255) | ((v.y & 255) << 8) |
                        ((v.z & 255) << 16) | ((v.w & 255) << 24);
    }
}

// ---------------- Kernel 3: 256x256 8-phase (m201 port) i8 GEMM -----------------
// i8 BK=128 elems = 128B rows == m201's bf16 BK=64 geometry exactly.
// 8 waves (2Mx4N), wave tile 128x64, mfma_i32_16x16x64_i8, acc[8][4] v4i.
// LDS: 2 sets x (A[256][128B] | B[256][128B]) = 128KB, granule swizzle
// slot = g ^ (row&7) (0-conflict, proven R7/R13), staged via pre-swizzled
// global source (linear gload_lds dest).
// Per iter (tiles T=set0, T+1=set1), 8 phases, each: {ds-reads | stage half}
// bar; lgkmcnt(0); prio1; 16 MFMA; prio0; [vmcnt]; bar.
// Stage plan (T+2 set0, T+3 set1; region >= last-read-phase + 1):
//   ph2: Bs0h0  ph3: Bs0h1  ph4: As0h0  ph5: As0h1  ph6: Bs1h0
//   ph7: Bs1h1, As1h0, As1h1
// vmcnt(4)@ph3 (drains prev-iter ph6/7 -> set1 ready), vmcnt(8)@ph7 (drains
// ph2-5 -> next set0 ready). Never below 4. Tail: ITER(14) no stage,
// vmcnt(0)@ph3.
__global__ __launch_bounds__(512, 1) void gemm_kernel(
    const int8_t* __restrict__ Ag,
    const int8_t* __restrict__ Bg,
    const float* __restrict__ xscale,
    const float* __restrict__ wscale,
    const float* __restrict__ bias,
    float* __restrict__ C, int M)
{
    __shared__ __align__(16) int8_t smem[2 * 65536];

    const int tid  = threadIdx.x;
    const int lane = tid & 63;
    const int wave = tid >> 6;
    const int wr = wave >> 2;          // 0..1
    const int wc = wave & 3;           // 0..3
    const int l15 = lane & 15, hi = lane >> 4;
    const int asw = l15 & 7;

    // XCD-bijective swizzle: 512 blocks = 8 XCDs x 64
    const int lb  = blockIdx.x;
    const int swb = (lb & 7) * 64 + (lb >> 3);
    const int bm = swb >> 3;
    const int bn = swb & 7;
    const size_t arow0 = (size_t)bm * BM;
    const size_t brow0 = (size_t)bn * BN;

    // staging: thread -> row tid>>3 (0..63), slot tid&7; source pre-swizzled
    const int st_r = tid >> 3;
    const int st_c = ((tid & 7) ^ ((tid >> 3) & 7)) << 4;

    int8_t* const s0 = (int8_t*)smem;
    int8_t* const s1 = (int8_t*)smem + 65536;

#define STA_H(SET, T, H)                                                         \
    do { _Pragma("unroll") for (int i_ = 0; i_ < 2; ++i_)                        \
        gload_lds16(Ag + (arow0 + (H) * 128 + i_ * 64 + st_r) * (size_t)IN_F     \
                        + (size_t)((T) * 128) + st_c,                            \
                    (int8_t*)smem + (SET) * 65536 + (H) * 16384 + i_ * 8192      \
                        + tid * 16);                                             \
    } while (0)

#define STB_H(SET, T, H)                                                         \
    do { _Pragma("unroll") for (int i_ = 0; i_ < 2; ++i_)                        \
        gload_lds16(Bg + (brow0 + (H) * 128 + i_ * 64 + st_r) * (size_t)IN_F     \
                        + (size_t)((T) * 128) + st_c,                            \
                    (int8_t*)smem + (SET) * 65536 + 32768 + (H) * 16384          \
                        + i_ * 8192 + tid * 16);                                 \
    } while (0)

    // A-frag: row = wr*128 + MH*64 + m*16 + l15; granule g = ks*4+hi, slot g^asw
#define RD_A(SB, MH)                                                             \
    do { _Pragma("unroll") for (int m_ = 0; m_ < 4; ++m_)                        \
         _Pragma("unroll") for (int ks_ = 0; ks_ < 2; ++ks_)                     \
        a[m_][ks_] = *(const v4i*)((SB) + (wr * 128 + (MH) * 64 + m_ * 16 + l15) \
                                   * 128 + (((ks_ * 4 + hi) ^ asw) << 4));       \
    } while (0)

    // B-frag: col-row = wc*64 + NH*32 + n*16 + l15
#define RD_B(SB, DST, NH)                                                        \
    do { _Pragma("unroll") for (int n_ = 0; n_ < 2; ++n_)                        \
         _Pragma("unroll") for (int ks_ = 0; ks_ < 2; ++ks_)                     \
        DST[n_][ks_] = *(const v4i*)((SB) + 32768 +                              \
                       (wc * 64 + (NH) * 32 + n_ * 16 + l15) * 128 +             \
                       (((ks_ * 4 + hi) ^ asw) << 4));                           \
    } while (0)

#define MFQ(MH, B, NH)                                                           \
    do { __builtin_amdgcn_s_setprio(1);                                          \
        _Pragma("unroll") for (int m_ = 0; m_ < 4; ++m_)                         \
        _Pragma("unroll") for (int n_ = 0; n_ < 2; ++n_)                         \
        _Pragma("unroll") for (int ks_ = 0; ks_ < 2; ++ks_)                      \
            acc[(MH) * 4 + m_][(NH) * 2 + n_] =                                  \
                __builtin_amdgcn_mfma_i32_16x16x64_i8(                           \
                    a[m_][ks_], B[n_][ks_], acc[(MH) * 4 + m_][(NH) * 2 + n_],   \
                    0, 0, 0);                                                    \
        __builtin_amdgcn_s_setprio(0); } while (0)

#define BAR __builtin_amdgcn_s_barrier()
#define LGK asm volatile("s_waitcnt lgkmcnt(0)" ::: "memory")
#define VMW4 asm volatile("s_waitcnt vmcnt(4)" ::: "memory")
#define VMW8 asm volatile("s_waitcnt vmcnt(8)" ::: "memory")
#define VMW0 asm volatile("s_waitcnt vmcnt(0)" ::: "memory")
#define VNOP ((void)0)

#define ITER(T, DO_S, W3, W7)                                                    \
    do {                                                                         \
        /* ph0 */ RD_A(s0, 0); RD_B(s0, bLo, 0);                                 \
        BAR; LGK; MFQ(0, bLo, 0); BAR;                                           \
        /* ph1 */ RD_B(s0, bHi, 1);                                              \
        BAR; LGK; MFQ(0, bHi, 1); BAR;                                           \
        /* ph2 */ RD_A(s0, 1); if (DO_S) STB_H(0, (T) + 2, 0);                   \
        BAR; LGK; MFQ(1, bHi, 1); BAR;                                           \
        /* ph3 */ if (DO_S) STB_H(0, (T) + 2, 1);                                \
        BAR; LGK; MFQ(1, bLo, 0); W3; BAR;                                       \
        /* ph4 */ RD_A(s1, 0); RD_B(s1, bLo, 0); if (DO_S) STA_H(0, (T) + 2, 0); \
        BAR; LGK; MFQ(0, bLo, 0); BAR;                                           \
        /* ph5 */ RD_B(s1, bHi, 1); if (DO_S) STA_H(0, (T) + 2, 1);              \
        BAR; LGK; MFQ(0, bHi, 1); BAR;                                           \
        /* ph6 */ RD_A(s1, 1); if (DO_S) STB_H(1, (T) + 3, 0);                   \
        BAR; LGK; MFQ(1, bHi, 1); BAR;                                           \
        /* ph7 */ if (DO_S) { STB_H(1, (T) + 3, 1);                              \
                              STA_H(1, (T) + 3, 0); STA_H(1, (T) + 3, 1); }      \
        BAR; LGK; MFQ(1, bLo, 0); W7; BAR;                                       \
    } while (0)

    v4i acc[8][4] = {};
    v4i a[4][2], bLo[2][2], bHi[2][2];

    // prologue: tile0 (A,B) then tile1 (A,B) = 16 issues; vmcnt(8) drains tile0.
    STA_H(0, 0, 0); STA_H(0, 0, 1); STB_H(0, 0, 0); STB_H(0, 0, 1);
    STA_H(1, 1, 0); STA_H(1, 1, 1); STB_H(1, 1, 0); STB_H(1, 1, 1);
    VMW8;
    BAR;

    ITER(0,  true,  VMW4, VMW8);
    ITER(2,  true,  VMW4, VMW8);
    ITER(4,  true,  VMW4, VMW8);
    ITER(6,  true,  VMW4, VMW8);
    ITER(8,  true,  VMW4, VMW8);
    ITER(10, true,  VMW4, VMW8);
    ITER(12, true,  VMW4, VMW8);
    ITER(14, false, VMW0, VNOP);

    // epilogue: 16x16 C/D: col = lane&15, row = hi*4 + reg
    float wsc[4], bs[4];
    int gcol[4];
#pragma unroll
    for (int n = 0; n < 4; ++n) {
        gcol[n] = bn * BN + wc * 64 + n * 16 + l15;
        wsc[n] = wscale[gcol[n]];
        bs[n]  = bias[gcol[n]];
    }
#pragma unroll
    for (int m = 0; m < 8; ++m) {
#pragma unroll
        for (int r = 0; r < 4; ++r) {
            const size_t grow = arow0 + wr * 128 + m * 16 + hi * 4 + r;
            const float xs = xscale[grow];
            float* crow = C + grow * OUT_F;
#pragma unroll
            for (int n = 0; n < 4; ++n)
                __builtin_nontemporal_store(
                    (float)acc[m][n][r] * xs * wsc[n] + bs[n], crow + gcol[n]);
        }
    }
#undef STA_H
#undef STB_H
#undef RD_A
#undef RD_B
#undef MFQ
#undef ITER
}

extern "C" void kernel_launch(void* const* d_in, const int* in_sizes, int n_in,
                              void* d_out, int out_size, void* d_ws, size_t ws_size,
                              hipStream_t stream)
{
    const float* x      = (const float*)d_in[0];
    const float* ss     = (const float*)d_in[1];
    const float* wscale = (const float*)d_in[2];
    const float* bias   = (const float*)d_in[3];
    const int*   w32    = (const int*)d_in[4];
    float* out = (float*)d_out;

    const int T = in_sizes[0] / IN_F;   // 16384

    int8_t* xq     = (int8_t*)d_ws;
    float*  xscale = (float*)((char*)d_ws + (size_t)T * IN_F);
    int8_t* w8     = (int8_t*)((char*)d_ws + (size_t)T * IN_F + (size_t)T * 4);

    quant_kernel<<<dim3((T + 3) / 4), dim3(256), 0, stream>>>(x, ss, xq, xscale, T);
    pack_w_kernel<<<dim3(OUT_F * IN_F / 4 / 256), dim3(256), 0, stream>>>(
        w32, w8, OUT_F * IN_F / 4);
    gemm_kernel<<<dim3((T / BM) * (OUT_F / BN)), dim3(512), 0, stream>>>(
        xq, w8, xscale, wscale, bias, out, T);
}

// Round 16
// 105.237 us; speedup vs baseline: 1.2770x; 1.0737x over previous
//
#include <hip/hip_runtime.h>
#include <stdint.h>

#define IN_F 2048
#define OUT_F 2048
#define BM 128
#define BN 256
#define NT 16               // K-tiles of 128 bytes

typedef int v4i  __attribute__((ext_vector_type(4)));
typedef int v16i __attribute__((ext_vector_type(16)));

__device__ __forceinline__ void gload_lds16(const void* g, void* l) {
    __builtin_amdgcn_global_load_lds(
        (const __attribute__((address_space(1))) void*)g,
        (__attribute__((address_space(3))) void*)l, 16, 0, 0);
}

// ---------------- Kernel 1: smooth-scale + per-token int8 quant ----------------
__global__ __launch_bounds__(256) void quant_kernel(
    const float* __restrict__ x, const float* __restrict__ ss,
    int8_t* __restrict__ xq, float* __restrict__ xscale, int T)
{
    const int wave = threadIdx.x >> 6;
    const int lane = threadIdx.x & 63;
    const int t = blockIdx.x * 4 + wave;
    if (t >= T) return;

    const float4* xrow = (const float4*)(x + (size_t)t * IN_F);
    const float4* ssv  = (const float4*)ss;

    float4 vals[8];
    float amax = 0.f;
#pragma unroll
    for (int it = 0; it < 8; ++it) {
        int idx = it * 64 + lane;
        float4 v = xrow[idx];
        float4 s = ssv[idx];
        v.x *= s.x; v.y *= s.y; v.z *= s.z; v.w *= s.w;
        vals[it] = v;
        amax = fmaxf(amax, fmaxf(fmaxf(fabsf(v.x), fabsf(v.y)),
                                 fmaxf(fabsf(v.z), fabsf(v.w))));
    }
#pragma unroll
    for (int o = 32; o; o >>= 1) amax = fmaxf(amax, __shfl_xor(amax, o, 64));

    float scale = fmaxf(amax * (1.0f / 127.0f), 1e-8f);
    float inv = 1.0f / scale;
    if (lane == 0) xscale[t] = scale;

    int* out = (int*)(xq + (size_t)t * IN_F);
#pragma unroll
    for (int it = 0; it < 8; ++it) {
        float4 v = vals[it];
        int q0 = (int)fminf(fmaxf(rintf(v.x * inv), -128.f), 127.f);
        int q1 = (int)fminf(fmaxf(rintf(v.y * inv), -128.f), 127.f);
        int q2 = (int)fminf(fmaxf(rintf(v.z * inv), -128.f), 127.f);
        int q3 = (int)fminf(fmaxf(rintf(v.w * inv), -128.f), 127.f);
        out[it * 64 + lane] = (q0 & 255) | ((q1 & 255) << 8) |
                              ((q2 & 255) << 16) | ((q3 & 255) << 24);
    }
}

// ---------------- Kernel 2: pack W into MFMA-fragment order ----------------
// Fragment (colblk, kt, ks), lane l holds 16B: col = colblk*32 + (l&31),
// k = kt*128 + ks*32 + (l>>5)*16 + 0..15.
// Byte addr = colblk*65536 + kt*4096 + ks*1024 + l*16.
__global__ __launch_bounds__(256) void pack_wfrag_kernel(
    const int* __restrict__ w, int8_t* __restrict__ w8f)
{
    const int tau = blockIdx.x * 256 + threadIdx.x;   // 0..262143
    const int lane = tau & 63;
    const int rest = tau >> 6;
    const int ks = rest & 3;
    const int kt = (rest >> 2) & 15;
    const int colblk = rest >> 6;
    const int col = colblk * 32 + (lane & 31);
    const int kbase = kt * 128 + ks * 32 + (lane >> 5) * 16;
    const int* src = w + (size_t)col * IN_F + kbase;
    int out[4];
#pragma unroll
    for (int d = 0; d < 4; ++d) {
        int4 v = *(const int4*)(src + d * 4);
        out[d] = (v.x & 255) | ((v.y & 255) << 8) |
                 ((v.z & 255) << 16) | ((v.w & 255) << 24);
    }
    *(int4*)(w8f + (size_t)tau * 16) = *(const int4*)out;
}

// ---------------- Kernel 3: 128x256 i8 GEMM, 4 waves (1Mx4N), 2 blocks/CU ----------
// Wave tile 128x64: m_rep=4, n_rep=2 -> each A ds_read feeds 2 MFMAs.
// A in LDS 3-deep (16KB slots, shared by all 4 waves); B fragment-direct from L2,
// distance-1 prefetch, 2 reg buffers. Per tile t: LOADB(t+1), STAGE_A(t+2),
// COMPUTE(t), vmcnt(4), barrier.
__global__ __launch_bounds__(256, 2) void gemm_kernel(
    const int8_t* __restrict__ Ag,    // [M, IN_F] quantized activations
    const int8_t* __restrict__ Bf,    // fragment-ordered weights
    const float* __restrict__ xscale,
    const float* __restrict__ wscale,
    const float* __restrict__ bias,
    float* __restrict__ C, int M)
{
    __shared__ __align__(16) int8_t smem[3 * 16384];   // 48 KB: 3 A-slots

    const int tid  = threadIdx.x;
    const int lane = tid & 63;
    const int wc   = tid >> 6;         // wave = N-quarter (0..3), 64 cols each
    const int l31 = lane & 31, hi2 = lane >> 5;
    const int asw = l31 & 7;

    // XCD-bijective swizzle: 1024 blocks, 8 XCDs, 128 per chunk
    const int lb  = blockIdx.x;
    const int swb = (lb & 7) * 128 + (lb >> 3);
    const int bm = swb >> 3;           // 0..127
    const int bn = swb & 7;            // 0..7
    const size_t arow0 = (size_t)bm * BM;

    // A staging: thread covers rows (tid>>3)+32*i, LDS slot (tid&7), pre-swizzled src
    const int st_r = tid >> 3;
    const int st_c = ((tid & 7) ^ ((tid >> 3) & 7)) << 4;

    // A ds_read base: row = m*32 + l31; granule g = ks*2+hi2 at slot col (g^asw)*16
    const int aoff = l31 * 128;

    // B fragment base: wave owns colblks bn*8 + wc*2 {+0,+1} (stride 65536 B)
    const int8_t* bbase = Bf + (size_t)(bn * 8 + wc * 2) * 65536 + lane * 16;

#define STAGE_A(SLOTI, T)                                                        \
    do { _Pragma("unroll") for (int i_ = 0; i_ < 4; ++i_)                        \
        gload_lds16(Ag + (arow0 + i_ * 32 + st_r) * (size_t)IN_F                 \
                        + (size_t)((T) * 128) + st_c,                            \
                    (int8_t*)smem + (SLOTI) * 16384 + i_ * 4096 + tid * 16);     \
    } while (0)

#define LOADB(DST, T)                                                            \
    do { _Pragma("unroll") for (int n_ = 0; n_ < 2; ++n_)                        \
         _Pragma("unroll") for (int k_ = 0; k_ < 4; ++k_)                        \
        DST[n_ * 4 + k_] = *(const v4i*)(bbase + n_ * 65536 + (T) * 4096         \
                                         + k_ * 1024);                           \
    } while (0)

#define RDA(AF, KS)                                                              \
    do { _Pragma("unroll") for (int m_ = 0; m_ < 4; ++m_)                        \
        AF[m_] = *(const v4i*)(sp_ + m_ * 4096 +                                 \
                               ((((KS) * 2 + hi2) ^ asw) << 4));                 \
    } while (0)

#define MFMA8(AF, B, KS)                                                         \
    do { __builtin_amdgcn_s_setprio(1);                                          \
        _Pragma("unroll") for (int m_ = 0; m_ < 4; ++m_)                         \
        _Pragma("unroll") for (int n_ = 0; n_ < 2; ++n_)                         \
            acc[m_][n_] = __builtin_amdgcn_mfma_i32_32x32x32_i8(                 \
                AF[m_], B[n_ * 4 + (KS)], acc[m_][n_], 0, 0, 0);                 \
        __builtin_amdgcn_s_setprio(0); } while (0)

#define COMPUTE(SLOTI, B)                                                        \
    do { const int8_t* sp_ = (const int8_t*)smem + (SLOTI) * 16384 + aoff;       \
        v4i a0_[4], a1_[4];                                                      \
        RDA(a0_, 0);                                                             \
        RDA(a1_, 1); MFMA8(a0_, B, 0);                                           \
        RDA(a0_, 2); MFMA8(a1_, B, 1);                                           \
        RDA(a1_, 3); MFMA8(a0_, B, 2);                                           \
        MFMA8(a1_, B, 3);                                                        \
    } while (0)

// Per-tile ledger (audited): issue LOADB(t+1)[8] then STAGE(t+2)[4].
// Steady outstanding at end = S(t+1)[4], B(t+1)[8], S(t+2)[4]; vmcnt(4)
// drains S(t+1)+B(t+1), leaves S(t+2) in flight. Never 0 until t=14.
#define TILE(T, BCUR, BNXT)                                                      \
    do {                                                                         \
        if ((T) <= 14) LOADB(BNXT, (T) + 1);                                     \
        if ((T) <= 13) STAGE_A(((T) + 2) % 3, (T) + 2);                          \
        COMPUTE((T) % 3, BCUR);                                                  \
        if ((T) <= 13) {                                                         \
            asm volatile("s_waitcnt vmcnt(4)" ::: "memory");                     \
            __builtin_amdgcn_s_barrier();                                        \
        } else if ((T) == 14) {                                                  \
            asm volatile("s_waitcnt vmcnt(0)" ::: "memory");                     \
            __builtin_amdgcn_s_barrier();                                        \
        }                                                                        \
    } while (0)

    v16i acc[4][2] = {};
    v4i B0[8], B1[8];

    // prologue: S(0)->slot0, B(0)->B0, S(1)->slot1; vmcnt(4) leaves S(1) in flight
    STAGE_A(0, 0);
    LOADB(B0, 0);
    STAGE_A(1, 1);
    asm volatile("s_waitcnt vmcnt(4)" ::: "memory");
    __builtin_amdgcn_s_barrier();

#pragma unroll
    for (int t = 0; t < NT; t += 2) {
        TILE(t, B0, B1);
        TILE(t + 1, B1, B0);
    }

    // epilogue: 32x32 C/D layout col = lane&31, row = (reg&3) + 8*(reg>>2) + 4*hi2
    float wsc[2], bs[2];
    int gcol[2];
#pragma unroll
    for (int n = 0; n < 2; ++n) {
        gcol[n] = bn * BN + wc * 64 + n * 32 + l31;
        wsc[n] = wscale[gcol[n]];
        bs[n]  = bias[gcol[n]];
    }
#pragma unroll
    for (int m = 0; m < 4; ++m) {
#pragma unroll
        for (int reg = 0; reg < 16; ++reg) {
            const int row = (reg & 3) + 8 * (reg >> 2) + 4 * hi2;
            const size_t grow = arow0 + m * 32 + row;
            const float xs = xscale[grow];
            float* crow = C + grow * OUT_F;
#pragma unroll
            for (int n = 0; n < 2; ++n)
                __builtin_nontemporal_store(
                    (float)acc[m][n][reg] * xs * wsc[n] + bs[n], crow + gcol[n]);
        }
    }
#undef STAGE_A
#undef LOADB
#undef RDA
#undef MFMA8
#undef COMPUTE
#undef TILE
}

extern "C" void kernel_launch(void* const* d_in, const int* in_sizes, int n_in,
                              void* d_out, int out_size, void* d_ws, size_t ws_size,
                              hipStream_t stream)
{
    const float* x      = (const float*)d_in[0];
    const float* ss     = (const float*)d_in[1];
    const float* wscale = (const float*)d_in[2];
    const float* bias   = (const float*)d_in[3];
    const int*   w32    = (const int*)d_in[4];
    float* out = (float*)d_out;

    const int T = in_sizes[0] / IN_F;   // 16384

    int8_t* xq     = (int8_t*)d_ws;
    float*  xscale = (float*)((char*)d_ws + (size_t)T * IN_F);
    int8_t* w8f    = (int8_t*)((char*)d_ws + (size_t)T * IN_F + (size_t)T * 4);

    quant_kernel<<<dim3((T + 3) / 4), dim3(256), 0, stream>>>(x, ss, xq, xscale, T);
    pack_wfrag_kernel<<<dim3(1024), dim3(256), 0, stream>>>(w32, w8f);
    gemm_kernel<<<dim3((T / BM) * (OUT_F / BN)), dim3(256), 0, stream>>>(
        xq, w8f, xscale, wscale, bias, out, T);
}